// Round 1
// baseline (530.949 us; speedup 1.0000x reference)
//
#include <hip/hip_runtime.h>
#include <hip/hip_bf16.h>
#include <cstdint>
#include <cstddef>

typedef float f32x4 __attribute__((ext_vector_type(4)));
typedef __bf16 bf16x8 __attribute__((ext_vector_type(8)));
typedef unsigned short us8v __attribute__((ext_vector_type(8)));
typedef unsigned short us4v __attribute__((ext_vector_type(4)));

constexpr int B_ = 2, S_ = 2048, D_ = 2048, NH = 16, NKV = 4, HD = 128;
constexpr int QKV_O = (NH + 2 * NKV) * HD;  // 3072

__device__ __forceinline__ unsigned short f2b(float f) {
  union { float f; uint32_t u; } v{f};
  uint32_t r = v.u + 0x7fffu + ((v.u >> 16) & 1u);  // RNE
  return (unsigned short)(r >> 16);
}

__device__ __forceinline__ bf16x8 as_bf(us8v x) {
  union { us8v u; bf16x8 b; } v; v.u = x; return v.b;
}

__device__ __forceinline__ f32x4 mfma16(bf16x8 a, bf16x8 b, f32x4 c) {
  return __builtin_amdgcn_mfma_f32_16x16x32_bf16(a, b, c, 0, 0, 0);
}

// ---------------- f32 -> bf16 conversion (vectorized) ----------------
__global__ void f2b_kernel(const float* __restrict__ in, unsigned short* __restrict__ out, int n4) {
  int i = blockIdx.x * blockDim.x + threadIdx.x;
  if (i >= n4) return;
  float4 v = reinterpret_cast<const float4*>(in)[i];
  us4v o;
  o[0] = f2b(v.x); o[1] = f2b(v.y); o[2] = f2b(v.z); o[3] = f2b(v.w);
  reinterpret_cast<us4v*>(out)[i] = o;
}

// ---------------- RoPE cos/sin table: [S][64] ----------------
__global__ void rope_table_kernel(float* __restrict__ cs, float* __restrict__ sn) {
  int idx = blockIdx.x * blockDim.x + threadIdx.x;
  if (idx >= S_ * 64) return;
  int t = idx >> 6, i = idx & 63;
  // inv_freq = theta^(-2i/128) = exp(-(2i/128)*ln(10000))
  float inv = __expf(-((float)(2 * i) / 128.0f) * 9.210340371976184f);
  float fr = (float)t * inv;
  cs[idx] = cosf(fr);
  sn[idx] = sinf(fr);
}

// ---------------- RoPE apply on Q,K; write bf16 [b,h,s,d] ----------------
__global__ void rope_qk_kernel(const float* __restrict__ qkv, const float* __restrict__ cs,
                               const float* __restrict__ sn, unsigned short* __restrict__ Q,
                               unsigned short* __restrict__ Kc) {
  int idx = blockIdx.x * blockDim.x + threadIdx.x;
  if (idx >= B_ * S_ * 20 * 64) return;
  int pr = idx & 63;
  int tmp = idx >> 6;
  int hh = tmp % 20; tmp /= 20;
  int s = tmp % S_;
  int b = tmp / S_;
  int off = (hh < 16) ? hh * HD : NH * HD + (hh - 16) * HD;
  float2 v = *reinterpret_cast<const float2*>(qkv + (size_t)(b * S_ + s) * QKV_O + off + 2 * pr);
  float c0 = cs[s * 64 + pr], s0 = sn[s * 64 + pr];
  float o0 = v.x * c0 - v.y * s0;
  float o1 = v.x * s0 + v.y * c0;
  unsigned int packed = (unsigned)f2b(o0) | ((unsigned)f2b(o1) << 16);
  if (hh < 16)
    *reinterpret_cast<unsigned*>(Q + (((size_t)(b * NH + hh) * S_ + s) * HD + 2 * pr)) = packed;
  else
    *reinterpret_cast<unsigned*>(Kc + (((size_t)(b * NKV + (hh - 16)) * S_ + s) * HD + 2 * pr)) = packed;
}

// ---------------- V transpose: qkv f32 -> Vt bf16 [b,kvh,d,s] ----------------
__global__ void vt_kernel(const float* __restrict__ qkv, unsigned short* __restrict__ Vt) {
  __shared__ unsigned short tile[32][33];
  int t = threadIdx.x;
  int tx = t & 31, ty = t >> 5;  // 32 x 8
  int s0 = blockIdx.x * 32, d0 = blockIdx.y * 32;
  int bk = blockIdx.z;  // b*4+kvh
  const float* src = qkv + (size_t)((bk >> 2) * S_) * QKV_O + (NH + NKV) * HD + (bk & 3) * HD;
#pragma unroll
  for (int i = 0; i < 4; i++) {
    int s = s0 + ty + i * 8;
    tile[ty + i * 8][tx] = f2b(src[(size_t)s * QKV_O + d0 + tx]);
  }
  __syncthreads();
#pragma unroll
  for (int i = 0; i < 4; i++) {
    int d = d0 + ty + i * 8;
    Vt[((size_t)bk * HD + d) * S_ + s0 + tx] = tile[tx][ty + i * 8];
  }
}

// ---------------- bf16 GEMM: C[M,N] = A[M,K] * B[N,K]^T (f32 out) ----------------
__global__ __launch_bounds__(256) void gemm_bt_kernel(const unsigned short* __restrict__ A,
                                                      const unsigned short* __restrict__ Bm,
                                                      float* __restrict__ C, int M, int N, int K) {
  __shared__ unsigned short As[128][40];
  __shared__ unsigned short Bs[128][40];
  int t = threadIdx.x;
  int lane = t & 63, wid = t >> 6;
  int wr = wid >> 1, wc = wid & 1;  // 2x2 wave grid, each wave 64x64
  int g = lane >> 4, c = lane & 15;
  int m0 = blockIdx.y * 128, n0 = blockIdx.x * 128;
  int sr = t >> 1, sk = (t & 1) * 16;
  const unsigned short* pa = A + (size_t)(m0 + sr) * K + sk;
  const unsigned short* pb = Bm + (size_t)(n0 + sr) * K + sk;
  f32x4 acc[4][4] = {};
  for (int k0 = 0; k0 < K; k0 += 32) {
    *reinterpret_cast<uint4*>(&As[sr][sk]) = *reinterpret_cast<const uint4*>(pa + k0);
    *reinterpret_cast<uint4*>(&As[sr][sk + 8]) = *reinterpret_cast<const uint4*>(pa + k0 + 8);
    *reinterpret_cast<uint4*>(&Bs[sr][sk]) = *reinterpret_cast<const uint4*>(pb + k0);
    *reinterpret_cast<uint4*>(&Bs[sr][sk + 8]) = *reinterpret_cast<const uint4*>(pb + k0 + 8);
    __syncthreads();
    bf16x8 af[4], bfv[4];
#pragma unroll
    for (int m = 0; m < 4; m++)
      af[m] = as_bf(*reinterpret_cast<const us8v*>(&As[wr * 64 + m * 16 + c][g * 8]));
#pragma unroll
    for (int n = 0; n < 4; n++)
      bfv[n] = as_bf(*reinterpret_cast<const us8v*>(&Bs[wc * 64 + n * 16 + c][g * 8]));
#pragma unroll
    for (int m = 0; m < 4; m++)
#pragma unroll
      for (int n = 0; n < 4; n++) acc[m][n] = mfma16(af[m], bfv[n], acc[m][n]);
    __syncthreads();
  }
#pragma unroll
  for (int m = 0; m < 4; m++)
#pragma unroll
    for (int n = 0; n < 4; n++)
#pragma unroll
      for (int r = 0; r < 4; r++)
        C[(size_t)(m0 + wr * 64 + m * 16 + g * 4 + r) * N + n0 + wc * 64 + n * 16 + c] =
            acc[m][n][r];
}

// ---------------- Flash attention: 1 wave per (b,h,16 q rows) ----------------
__global__ __launch_bounds__(64) void attn_kernel(const unsigned short* __restrict__ Q,
                                                  const unsigned short* __restrict__ Kc,
                                                  const unsigned short* __restrict__ Vt,
                                                  unsigned short* __restrict__ O) {
  int lane = threadIdx.x;
  int g = lane >> 4, c = lane & 15;
  int q0 = blockIdx.x * 16;
  int bh = blockIdx.y;
  int b = bh >> 4, h = bh & 15;
  int kvh = h >> 2;
  const unsigned short* Qp = Q + ((size_t)(b * NH + h) * S_ + q0) * HD;
  const unsigned short* Kp = Kc + (size_t)(b * NKV + kvh) * S_ * HD;
  const unsigned short* Vp = Vt + (size_t)(b * NKV + kvh) * HD * S_;

  bf16x8 qf[4];
#pragma unroll
  for (int kk = 0; kk < 4; kk++)
    qf[kk] = as_bf(*reinterpret_cast<const us8v*>(Qp + (size_t)c * HD + kk * 32 + g * 8));

  f32x4 acc[8] = {};
  float mrow[4], lrow[4];
#pragma unroll
  for (int r = 0; r < 4; r++) { mrow[r] = -1e30f; lrow[r] = 0.0f; }

  __shared__ unsigned short P[16][40];
  const float scale = 0.08838834764831845f;

  for (int kv0 = 0; kv0 < q0 + 16; kv0 += 32) {
    f32x4 s0 = {}, s1 = {};
    const unsigned short* k0p = Kp + (size_t)(kv0 + c) * HD;
#pragma unroll
    for (int kk = 0; kk < 4; kk++) {
      s0 = mfma16(qf[kk], as_bf(*reinterpret_cast<const us8v*>(k0p + kk * 32 + g * 8)), s0);
      s1 = mfma16(qf[kk], as_bf(*reinterpret_cast<const us8v*>(k0p + 16 * HD + kk * 32 + g * 8)), s1);
    }
    int row = q0 + g * 4;
#pragma unroll
    for (int r = 0; r < 4; r++) {
      float a0 = s0[r] * scale, a1 = s1[r] * scale;
      if (kv0 + c > row + r) a0 = -1e30f;
      if (kv0 + 16 + c > row + r) a1 = -1e30f;
      s0[r] = a0; s1[r] = a1;
    }
    float p0[4], p1[4], alpha[4];
#pragma unroll
    for (int r = 0; r < 4; r++) {
      float mx = fmaxf(s0[r], s1[r]);
      mx = fmaxf(mx, __shfl_xor(mx, 1));
      mx = fmaxf(mx, __shfl_xor(mx, 2));
      mx = fmaxf(mx, __shfl_xor(mx, 4));
      mx = fmaxf(mx, __shfl_xor(mx, 8));
      float mn = fmaxf(mrow[r], mx);
      alpha[r] = __expf(mrow[r] - mn);
      mrow[r] = mn;
      p0[r] = __expf(s0[r] - mn);
      p1[r] = __expf(s1[r] - mn);
      float rs = p0[r] + p1[r];
      rs += __shfl_xor(rs, 1);
      rs += __shfl_xor(rs, 2);
      rs += __shfl_xor(rs, 4);
      rs += __shfl_xor(rs, 8);
      lrow[r] = lrow[r] * alpha[r] + rs;
    }
#pragma unroll
    for (int tt = 0; tt < 8; tt++)
#pragma unroll
      for (int r = 0; r < 4; r++) acc[tt][r] *= alpha[r];
    __syncthreads();  // previous iteration's P reads complete
#pragma unroll
    for (int r = 0; r < 4; r++) {
      P[g * 4 + r][c] = f2b(p0[r]);
      P[g * 4 + r][16 + c] = f2b(p1[r]);
    }
    __syncthreads();
    bf16x8 pa = as_bf(*reinterpret_cast<const us8v*>(&P[c][g * 8]));
#pragma unroll
    for (int tt = 0; tt < 8; tt++) {
      bf16x8 vf = as_bf(*reinterpret_cast<const us8v*>(Vp + (size_t)(tt * 16 + c) * S_ + kv0 + g * 8));
      acc[tt] = mfma16(pa, vf, acc[tt]);
    }
  }
#pragma unroll
  for (int tt = 0; tt < 8; tt++)
#pragma unroll
    for (int r = 0; r < 4; r++) {
      float v = acc[tt][r] / lrow[r];
      O[((size_t)b * S_ + q0 + g * 4 + r) * D_ + h * HD + tt * 16 + c] = f2b(v);
    }
}

extern "C" void kernel_launch(void* const* d_in, const int* in_sizes, int n_in, void* d_out,
                              int out_size, void* d_ws, size_t ws_size, hipStream_t stream) {
  const float* x = (const float*)d_in[0];
  const float* w_qkv = (const float*)d_in[1];
  const float* w_o = (const float*)d_in[2];
  float* out = (float*)d_out;

  char* ws = (char*)d_ws;
  size_t off = 0;
  auto alloc = [&](size_t bytes) -> void* {
    void* p = ws + off;
    off += (bytes + 255) & ~(size_t)255;
    return p;
  };
  const size_t nx = (size_t)B_ * S_ * D_;                 // 8388608
  const size_t nwqkv = (size_t)QKV_O * D_;                // 6291456
  const size_t nwo = (size_t)D_ * D_;                     // 4194304
  unsigned short* xb = (unsigned short*)alloc(nx * 2);
  unsigned short* wqkvb = (unsigned short*)alloc(nwqkv * 2);
  unsigned short* wob = (unsigned short*)alloc(nwo * 2);
  float* qkv = (float*)alloc((size_t)B_ * S_ * QKV_O * 4);
  unsigned short* Qb = (unsigned short*)alloc((size_t)B_ * NH * S_ * HD * 2);
  unsigned short* Kb = (unsigned short*)alloc((size_t)B_ * NKV * S_ * HD * 2);
  unsigned short* Vtb = (unsigned short*)alloc((size_t)B_ * NKV * HD * S_ * 2);
  unsigned short* attnb = (unsigned short*)alloc((size_t)B_ * S_ * D_ * 2);
  float* cs = (float*)alloc((size_t)S_ * 64 * 4);
  float* sn = (float*)alloc((size_t)S_ * 64 * 4);

  f2b_kernel<<<dim3((nx / 4 + 255) / 256), 256, 0, stream>>>(x, xb, nx / 4);
  f2b_kernel<<<dim3((nwqkv / 4 + 255) / 256), 256, 0, stream>>>(w_qkv, wqkvb, nwqkv / 4);
  f2b_kernel<<<dim3((nwo / 4 + 255) / 256), 256, 0, stream>>>(w_o, wob, nwo / 4);
  rope_table_kernel<<<dim3((S_ * 64 + 255) / 256), 256, 0, stream>>>(cs, sn);

  gemm_bt_kernel<<<dim3(QKV_O / 128, (B_ * S_) / 128), 256, 0, stream>>>(xb, wqkvb, qkv,
                                                                         B_ * S_, QKV_O, D_);

  rope_qk_kernel<<<dim3((B_ * S_ * 20 * 64 + 255) / 256), 256, 0, stream>>>(qkv, cs, sn, Qb, Kb);
  vt_kernel<<<dim3(S_ / 32, HD / 32, B_ * NKV), 256, 0, stream>>>(qkv, Vtb);

  attn_kernel<<<dim3(S_ / 16, B_ * NH), 64, 0, stream>>>(Qb, Kb, Vtb, attnb);

  gemm_bt_kernel<<<dim3(D_ / 128, (B_ * S_) / 128), 256, 0, stream>>>(attnb, wob, out,
                                                                      B_ * S_, D_, D_);
}

// Round 2
// 418.045 us; speedup vs baseline: 1.2701x; 1.2701x over previous
//
#include <hip/hip_runtime.h>
#include <hip/hip_bf16.h>
#include <cstdint>
#include <cstddef>

typedef float f32x4 __attribute__((ext_vector_type(4)));
typedef float f32x16 __attribute__((ext_vector_type(16)));
typedef __bf16 bf16x8 __attribute__((ext_vector_type(8)));
typedef unsigned short us8v __attribute__((ext_vector_type(8)));
typedef unsigned short us4v __attribute__((ext_vector_type(4)));

constexpr int B_ = 2, S_ = 2048, D_ = 2048, NH = 16, NKV = 4, HD = 128;
constexpr int QKV_O = (NH + 2 * NKV) * HD;  // 3072

__device__ __forceinline__ unsigned short f2b(float f) {
  union { float f; uint32_t u; } v{f};
  uint32_t r = v.u + 0x7fffu + ((v.u >> 16) & 1u);  // RNE
  return (unsigned short)(r >> 16);
}

__device__ __forceinline__ uint32_t pk2(float a, float b) {
  union { __bf16 h[2]; uint32_t u; } v;
  v.h[0] = (__bf16)a; v.h[1] = (__bf16)b;
  return v.u;
}

__device__ __forceinline__ bf16x8 as_bf(us8v x) {
  union { us8v u; bf16x8 b; } v; v.u = x; return v.b;
}

__device__ __forceinline__ f32x4 mfma16(bf16x8 a, bf16x8 b, f32x4 c) {
  return __builtin_amdgcn_mfma_f32_16x16x32_bf16(a, b, c, 0, 0, 0);
}
__device__ __forceinline__ f32x16 mfma32(bf16x8 a, bf16x8 b, f32x16 c) {
  return __builtin_amdgcn_mfma_f32_32x32x16_bf16(a, b, c, 0, 0, 0);
}

// ---------------- f32 -> bf16 conversion (vectorized) ----------------
__global__ void f2b_kernel(const float* __restrict__ in, unsigned short* __restrict__ out, int n4) {
  int i = blockIdx.x * blockDim.x + threadIdx.x;
  if (i >= n4) return;
  float4 v = reinterpret_cast<const float4*>(in)[i];
  us4v o;
  o[0] = f2b(v.x); o[1] = f2b(v.y); o[2] = f2b(v.z); o[3] = f2b(v.w);
  reinterpret_cast<us4v*>(out)[i] = o;
}

// ---------------- RoPE cos/sin table: [S][64] ----------------
__global__ void rope_table_kernel(float* __restrict__ cs, float* __restrict__ sn) {
  int idx = blockIdx.x * blockDim.x + threadIdx.x;
  if (idx >= S_ * 64) return;
  int t = idx >> 6, i = idx & 63;
  float inv = __expf(-((float)(2 * i) / 128.0f) * 9.210340371976184f);
  float fr = (float)t * inv;
  cs[idx] = cosf(fr);
  sn[idx] = sinf(fr);
}

// ---------------- RoPE apply on Q,K; write bf16 [b,h,s,d]; Q pre-scaled ----------------
__global__ void rope_qk_kernel(const float* __restrict__ qkv, const float* __restrict__ cs,
                               const float* __restrict__ sn, unsigned short* __restrict__ Q,
                               unsigned short* __restrict__ Kc) {
  int idx = blockIdx.x * blockDim.x + threadIdx.x;
  if (idx >= B_ * S_ * 20 * 64) return;
  int pr = idx & 63;
  int tmp = idx >> 6;
  int hh = tmp % 20; tmp /= 20;
  int s = tmp % S_;
  int b = tmp / S_;
  int off = (hh < 16) ? hh * HD : NH * HD + (hh - 16) * HD;
  float2 v = *reinterpret_cast<const float2*>(qkv + (size_t)(b * S_ + s) * QKV_O + off + 2 * pr);
  float c0 = cs[s * 64 + pr], s0 = sn[s * 64 + pr];
  float mult = (hh < 16) ? 0.08838834764831845f : 1.0f;  // fold attn scale into Q
  float o0 = (v.x * c0 - v.y * s0) * mult;
  float o1 = (v.x * s0 + v.y * c0) * mult;
  unsigned int packed = (unsigned)f2b(o0) | ((unsigned)f2b(o1) << 16);
  if (hh < 16)
    *reinterpret_cast<unsigned*>(Q + (((size_t)(b * NH + hh) * S_ + s) * HD + 2 * pr)) = packed;
  else
    *reinterpret_cast<unsigned*>(Kc + (((size_t)(b * NKV + (hh - 16)) * S_ + s) * HD + 2 * pr)) = packed;
}

// ---------------- V transpose: qkv f32 -> Vt bf16 [b,kvh,d,s] ----------------
__global__ void vt_kernel(const float* __restrict__ qkv, unsigned short* __restrict__ Vt) {
  __shared__ unsigned short tile[32][33];
  int t = threadIdx.x;
  int tx = t & 31, ty = t >> 5;  // 32 x 8
  int s0 = blockIdx.x * 32, d0 = blockIdx.y * 32;
  int bk = blockIdx.z;  // b*4+kvh
  const float* src = qkv + (size_t)((bk >> 2) * S_) * QKV_O + (NH + NKV) * HD + (bk & 3) * HD;
#pragma unroll
  for (int i = 0; i < 4; i++) {
    int s = s0 + ty + i * 8;
    tile[ty + i * 8][tx] = f2b(src[(size_t)s * QKV_O + d0 + tx]);
  }
  __syncthreads();
#pragma unroll
  for (int i = 0; i < 4; i++) {
    int d = d0 + ty + i * 8;
    Vt[((size_t)bk * HD + d) * S_ + s0 + tx] = tile[tx][ty + i * 8];
  }
}

// ---------------- bf16 GEMM: C[M,N] = A[M,K] * B[N,K]^T (f32 out) ----------------
__global__ __launch_bounds__(256) void gemm_bt_kernel(const unsigned short* __restrict__ A,
                                                      const unsigned short* __restrict__ Bm,
                                                      float* __restrict__ C, int M, int N, int K) {
  __shared__ unsigned short As[128][40];
  __shared__ unsigned short Bs[128][40];
  int t = threadIdx.x;
  int lane = t & 63, wid = t >> 6;
  int wr = wid >> 1, wc = wid & 1;  // 2x2 wave grid, each wave 64x64
  int g = lane >> 4, c = lane & 15;
  int m0 = blockIdx.y * 128, n0 = blockIdx.x * 128;
  int sr = t >> 1, sk = (t & 1) * 16;
  const unsigned short* pa = A + (size_t)(m0 + sr) * K + sk;
  const unsigned short* pb = Bm + (size_t)(n0 + sr) * K + sk;
  f32x4 acc[4][4] = {};
  for (int k0 = 0; k0 < K; k0 += 32) {
    *reinterpret_cast<uint4*>(&As[sr][sk]) = *reinterpret_cast<const uint4*>(pa + k0);
    *reinterpret_cast<uint4*>(&As[sr][sk + 8]) = *reinterpret_cast<const uint4*>(pa + k0 + 8);
    *reinterpret_cast<uint4*>(&Bs[sr][sk]) = *reinterpret_cast<const uint4*>(pb + k0);
    *reinterpret_cast<uint4*>(&Bs[sr][sk + 8]) = *reinterpret_cast<const uint4*>(pb + k0 + 8);
    __syncthreads();
    bf16x8 af[4], bfv[4];
#pragma unroll
    for (int m = 0; m < 4; m++)
      af[m] = as_bf(*reinterpret_cast<const us8v*>(&As[wr * 64 + m * 16 + c][g * 8]));
#pragma unroll
    for (int n = 0; n < 4; n++)
      bfv[n] = as_bf(*reinterpret_cast<const us8v*>(&Bs[wc * 64 + n * 16 + c][g * 8]));
#pragma unroll
    for (int m = 0; m < 4; m++)
#pragma unroll
      for (int n = 0; n < 4; n++) acc[m][n] = mfma16(af[m], bfv[n], acc[m][n]);
    __syncthreads();
  }
#pragma unroll
  for (int m = 0; m < 4; m++)
#pragma unroll
    for (int n = 0; n < 4; n++)
#pragma unroll
      for (int r = 0; r < 4; r++)
        C[(size_t)(m0 + wr * 64 + m * 16 + g * 4 + r) * N + n0 + wc * 64 + n * 16 + c] =
            acc[m][n][r];
}

// ---------------- Flash attention: swapped-QK^T 32x32 MFMA, 4 waves/block ----------------
// Wave owns 32 q rows (q = lane&31). S-tile: lane holds S[kv=(r&3)+8*(r>>2)+4*hi][q=lane&31].
// Softmax lane-local; P->A-frag via 8 pk2 + 8 shfl_xor(32). No LDS, no barriers.
__global__ __launch_bounds__(256, 2) void attn32_kernel(const unsigned short* __restrict__ Q,
                                                        const unsigned short* __restrict__ Kc,
                                                        const unsigned short* __restrict__ Vt,
                                                        unsigned short* __restrict__ O) {
  int t = threadIdx.x;
  int lane = t & 63, wid = t >> 6;
  int l31 = lane & 31, hi = lane >> 5;
  int qi = (int)gridDim.x - 1 - (int)blockIdx.x;  // heavy q-tiles dispatched first
  int bh = blockIdx.y;
  int b = bh >> 4, h = bh & 15, kvh = h >> 2;
  int qw = qi * 128 + wid * 32;

  const unsigned short* Qp = Q + ((size_t)(b * NH + h) * S_ + qw) * HD + (size_t)l31 * HD + hi * 8;
  const unsigned short* Kp = Kc + (size_t)(b * NKV + kvh) * S_ * HD + (size_t)l31 * HD + hi * 8;
  const unsigned short* Vp = Vt + (size_t)(b * NKV + kvh) * HD * S_ + (size_t)l31 * S_ + hi * 8;

  bf16x8 qf[8];
#pragma unroll
  for (int kk = 0; kk < 8; kk++)
    qf[kk] = as_bf(*reinterpret_cast<const us8v*>(Qp + kk * 16));

  f32x16 oacc[4] = {};
  float mrow = -1e30f, lsum = 0.0f;

  for (int kv0 = 0; kv0 <= qw; kv0 += 32) {
    // ---- QK^T: S[kv][q], A=K rows, B=Q cols ----
    f32x16 s = {};
    const unsigned short* kp = Kp + (size_t)kv0 * HD;
#pragma unroll
    for (int kk = 0; kk < 8; kk++)
      s = mfma32(as_bf(*reinterpret_cast<const us8v*>(kp + kk * 16)), qf[kk], s);

    if (kv0 == qw) {  // diagonal block: causal mask
      int qg = qw + l31;
#pragma unroll
      for (int r = 0; r < 16; r++) {
        int kvg = kv0 + (r & 3) + 8 * (r >> 2) + 4 * hi;
        if (kvg > qg) s[r] = -1e30f;
      }
    }

    // ---- online softmax (lane-local row; partner = lane^32) ----
    float pm = fmaxf(s[0], s[1]);
#pragma unroll
    for (int r = 2; r < 16; r++) pm = fmaxf(pm, s[r]);
    pm = fmaxf(pm, __shfl_xor(pm, 32));

    bool nore = __all(pm <= mrow + 8.0f) != 0;  // defer-max (T13), wave-uniform
    float mn = nore ? mrow : fmaxf(mrow, pm);
    float pr[16], part = 0.0f;
#pragma unroll
    for (int r = 0; r < 16; r++) { pr[r] = __expf(s[r] - mn); part += pr[r]; }
    part += __shfl_xor(part, 32);
    if (nore) {
      lsum += part;
    } else {
      float alpha = __expf(mrow - mn);
      lsum = lsum * alpha + part;
      mrow = mn;
#pragma unroll
      for (int dt = 0; dt < 4; dt++)
#pragma unroll
        for (int r = 0; r < 16; r++) oacc[dt][r] *= alpha;
    }

    // ---- P -> A-fragments (kv ascending) via pack + lane^32 exchange ----
    uint32_t w[8], sw[8];
#pragma unroll
    for (int j = 0; j < 8; j++) w[j] = pk2(pr[2 * j], pr[2 * j + 1]);
#pragma unroll
    for (int j = 0; j < 8; j++) sw[j] = __shfl_xor(w[j], 32);
    union { uint32_t u[4]; bf16x8 v; } pa0, pa1;
    if (hi == 0) {
      pa0.u[0] = w[0]; pa0.u[1] = w[1]; pa0.u[2] = sw[0]; pa0.u[3] = sw[1];
      pa1.u[0] = w[4]; pa1.u[1] = w[5]; pa1.u[2] = sw[4]; pa1.u[3] = sw[5];
    } else {
      pa0.u[0] = sw[2]; pa0.u[1] = sw[3]; pa0.u[2] = w[2]; pa0.u[3] = w[3];
      pa1.u[0] = sw[6]; pa1.u[1] = sw[7]; pa1.u[2] = w[6]; pa1.u[3] = w[7];
    }

    // ---- PV: O[q][d] += P * V, A=P rows(q), B=V^T cols(d) ----
    const unsigned short* vp = Vp + kv0;
#pragma unroll
    for (int dt = 0; dt < 4; dt++) {
      bf16x8 v0 = as_bf(*reinterpret_cast<const us8v*>(vp + (size_t)dt * 32 * S_));
      bf16x8 v1 = as_bf(*reinterpret_cast<const us8v*>(vp + (size_t)dt * 32 * S_ + 16));
      oacc[dt] = mfma32(pa0.v, v0, oacc[dt]);
      oacc[dt] = mfma32(pa1.v, v1, oacc[dt]);
    }
  }

  // ---- epilogue: O[q=crow(r,hi)][d=dt*32+l31] ----
  float il = 1.0f / lsum;
  unsigned short* Op = O + ((size_t)b * S_ + qw) * D_ + h * HD;
#pragma unroll
  for (int r = 0; r < 16; r++) {
    int row = (r & 3) + 8 * (r >> 2) + 4 * hi;
    float sc = __shfl(il, row);
#pragma unroll
    for (int dt = 0; dt < 4; dt++)
      Op[(size_t)row * D_ + dt * 32 + l31] = f2b(oacc[dt][r] * sc);
  }
}

extern "C" void kernel_launch(void* const* d_in, const int* in_sizes, int n_in, void* d_out,
                              int out_size, void* d_ws, size_t ws_size, hipStream_t stream) {
  const float* x = (const float*)d_in[0];
  const float* w_qkv = (const float*)d_in[1];
  const float* w_o = (const float*)d_in[2];
  float* out = (float*)d_out;

  char* ws = (char*)d_ws;
  size_t off = 0;
  auto alloc = [&](size_t bytes) -> void* {
    void* p = ws + off;
    off += (bytes + 255) & ~(size_t)255;
    return p;
  };
  const size_t nx = (size_t)B_ * S_ * D_;
  const size_t nwqkv = (size_t)QKV_O * D_;
  const size_t nwo = (size_t)D_ * D_;
  unsigned short* xb = (unsigned short*)alloc(nx * 2);
  unsigned short* wqkvb = (unsigned short*)alloc(nwqkv * 2);
  unsigned short* wob = (unsigned short*)alloc(nwo * 2);
  float* qkv = (float*)alloc((size_t)B_ * S_ * QKV_O * 4);
  unsigned short* Qb = (unsigned short*)alloc((size_t)B_ * NH * S_ * HD * 2);
  unsigned short* Kb = (unsigned short*)alloc((size_t)B_ * NKV * S_ * HD * 2);
  unsigned short* Vtb = (unsigned short*)alloc((size_t)B_ * NKV * HD * S_ * 2);
  unsigned short* attnb = (unsigned short*)alloc((size_t)B_ * S_ * D_ * 2);
  float* cs = (float*)alloc((size_t)S_ * 64 * 4);
  float* sn = (float*)alloc((size_t)S_ * 64 * 4);

  f2b_kernel<<<dim3((nx / 4 + 255) / 256), 256, 0, stream>>>(x, xb, nx / 4);
  f2b_kernel<<<dim3((nwqkv / 4 + 255) / 256), 256, 0, stream>>>(w_qkv, wqkvb, nwqkv / 4);
  f2b_kernel<<<dim3((nwo / 4 + 255) / 256), 256, 0, stream>>>(w_o, wob, nwo / 4);
  rope_table_kernel<<<dim3((S_ * 64 + 255) / 256), 256, 0, stream>>>(cs, sn);

  gemm_bt_kernel<<<dim3(QKV_O / 128, (B_ * S_) / 128), 256, 0, stream>>>(xb, wqkvb, qkv,
                                                                         B_ * S_, QKV_O, D_);

  rope_qk_kernel<<<dim3((B_ * S_ * 20 * 64 + 255) / 256), 256, 0, stream>>>(qkv, cs, sn, Qb, Kb);
  vt_kernel<<<dim3(S_ / 32, HD / 32, B_ * NKV), 256, 0, stream>>>(qkv, Vtb);

  attn32_kernel<<<dim3(16, 32), 256, 0, stream>>>(Qb, Kb, Vtb, attnb);

  gemm_bt_kernel<<<dim3(D_ / 128, (B_ * S_) / 128), 256, 0, stream>>>(attnb, wob, out,
                                                                      B_ * S_, D_, D_);
}

// Round 3
// 402.119 us; speedup vs baseline: 1.3204x; 1.0396x over previous
//
#include <hip/hip_runtime.h>
#include <hip/hip_bf16.h>
#include <cstdint>
#include <cstddef>

typedef float f32x4 __attribute__((ext_vector_type(4)));
typedef float f32x16 __attribute__((ext_vector_type(16)));
typedef __bf16 bf16x8 __attribute__((ext_vector_type(8)));
typedef unsigned short us8v __attribute__((ext_vector_type(8)));
typedef unsigned short us4v __attribute__((ext_vector_type(4)));

constexpr int B_ = 2, S_ = 2048, D_ = 2048, NH = 16, NKV = 4, HD = 128;
constexpr int QKV_O = (NH + 2 * NKV) * HD;  // 3072

__device__ __forceinline__ unsigned short f2b(float f) {
  union { float f; uint32_t u; } v{f};
  uint32_t r = v.u + 0x7fffu + ((v.u >> 16) & 1u);  // RNE
  return (unsigned short)(r >> 16);
}

__device__ __forceinline__ uint32_t pk2(float a, float b) {
  union { __bf16 h[2]; uint32_t u; } v;
  v.h[0] = (__bf16)a; v.h[1] = (__bf16)b;
  return v.u;
}

__device__ __forceinline__ bf16x8 as_bf(us8v x) {
  union { us8v u; bf16x8 b; } v; v.u = x; return v.b;
}

__device__ __forceinline__ f32x4 mfma16(bf16x8 a, bf16x8 b, f32x4 c) {
  return __builtin_amdgcn_mfma_f32_16x16x32_bf16(a, b, c, 0, 0, 0);
}
__device__ __forceinline__ f32x16 mfma32(bf16x8 a, bf16x8 b, f32x16 c) {
  return __builtin_amdgcn_mfma_f32_32x32x16_bf16(a, b, c, 0, 0, 0);
}

// ---------------- f32 -> bf16 conversion (vectorized) ----------------
__global__ void f2b_kernel(const float* __restrict__ in, unsigned short* __restrict__ out, int n4) {
  int i = blockIdx.x * blockDim.x + threadIdx.x;
  if (i >= n4) return;
  float4 v = reinterpret_cast<const float4*>(in)[i];
  us4v o;
  o[0] = f2b(v.x); o[1] = f2b(v.y); o[2] = f2b(v.z); o[3] = f2b(v.w);
  reinterpret_cast<us4v*>(out)[i] = o;
}

// ---------------- RoPE cos/sin table: [S][64] ----------------
__global__ void rope_table_kernel(float* __restrict__ cs, float* __restrict__ sn) {
  int idx = blockIdx.x * blockDim.x + threadIdx.x;
  if (idx >= S_ * 64) return;
  int t = idx >> 6, i = idx & 63;
  float inv = __expf(-((float)(2 * i) / 128.0f) * 9.210340371976184f);
  float fr = (float)t * inv;
  cs[idx] = cosf(fr);
  sn[idx] = sinf(fr);
}

// ---------------- RoPE apply on Q,K; write bf16 [b,h,s,d]; Q pre-scaled ----------------
__global__ void rope_qk_kernel(const float* __restrict__ qkv, const float* __restrict__ cs,
                               const float* __restrict__ sn, unsigned short* __restrict__ Q,
                               unsigned short* __restrict__ Kc) {
  int idx = blockIdx.x * blockDim.x + threadIdx.x;
  if (idx >= B_ * S_ * 20 * 64) return;
  int pr = idx & 63;
  int tmp = idx >> 6;
  int hh = tmp % 20; tmp /= 20;
  int s = tmp % S_;
  int b = tmp / S_;
  int off = (hh < 16) ? hh * HD : NH * HD + (hh - 16) * HD;
  float2 v = *reinterpret_cast<const float2*>(qkv + (size_t)(b * S_ + s) * QKV_O + off + 2 * pr);
  float c0 = cs[s * 64 + pr], s0 = sn[s * 64 + pr];
  float mult = (hh < 16) ? 0.08838834764831845f : 1.0f;  // fold attn scale into Q
  float o0 = (v.x * c0 - v.y * s0) * mult;
  float o1 = (v.x * s0 + v.y * c0) * mult;
  unsigned int packed = (unsigned)f2b(o0) | ((unsigned)f2b(o1) << 16);
  if (hh < 16)
    *reinterpret_cast<unsigned*>(Q + (((size_t)(b * NH + hh) * S_ + s) * HD + 2 * pr)) = packed;
  else
    *reinterpret_cast<unsigned*>(Kc + (((size_t)(b * NKV + (hh - 16)) * S_ + s) * HD + 2 * pr)) = packed;
}

// ---------------- V transpose: qkv f32 -> Vt bf16 [b,kvh,d,s] ----------------
__global__ void vt_kernel(const float* __restrict__ qkv, unsigned short* __restrict__ Vt) {
  __shared__ unsigned short tile[32][33];
  int t = threadIdx.x;
  int tx = t & 31, ty = t >> 5;  // 32 x 8
  int s0 = blockIdx.x * 32, d0 = blockIdx.y * 32;
  int bk = blockIdx.z;  // b*4+kvh
  const float* src = qkv + (size_t)((bk >> 2) * S_) * QKV_O + (NH + NKV) * HD + (bk & 3) * HD;
#pragma unroll
  for (int i = 0; i < 4; i++) {
    int s = s0 + ty + i * 8;
    tile[ty + i * 8][tx] = f2b(src[(size_t)s * QKV_O + d0 + tx]);
  }
  __syncthreads();
#pragma unroll
  for (int i = 0; i < 4; i++) {
    int d = d0 + ty + i * 8;
    Vt[((size_t)bk * HD + d) * S_ + s0 + tx] = tile[tx][ty + i * 8];
  }
}

// ---------------- bf16 GEMM: C[M,N] = A[M,K] * B[N,K]^T (f32 out) ----------------
__global__ __launch_bounds__(256) void gemm_bt_kernel(const unsigned short* __restrict__ A,
                                                      const unsigned short* __restrict__ Bm,
                                                      float* __restrict__ C, int M, int N, int K) {
  __shared__ unsigned short As[128][40];
  __shared__ unsigned short Bs[128][40];
  int t = threadIdx.x;
  int lane = t & 63, wid = t >> 6;
  int wr = wid >> 1, wc = wid & 1;  // 2x2 wave grid, each wave 64x64
  int g = lane >> 4, c = lane & 15;
  int m0 = blockIdx.y * 128, n0 = blockIdx.x * 128;
  int sr = t >> 1, sk = (t & 1) * 16;
  const unsigned short* pa = A + (size_t)(m0 + sr) * K + sk;
  const unsigned short* pb = Bm + (size_t)(n0 + sr) * K + sk;
  f32x4 acc[4][4] = {};
  for (int k0 = 0; k0 < K; k0 += 32) {
    *reinterpret_cast<uint4*>(&As[sr][sk]) = *reinterpret_cast<const uint4*>(pa + k0);
    *reinterpret_cast<uint4*>(&As[sr][sk + 8]) = *reinterpret_cast<const uint4*>(pa + k0 + 8);
    *reinterpret_cast<uint4*>(&Bs[sr][sk]) = *reinterpret_cast<const uint4*>(pb + k0);
    *reinterpret_cast<uint4*>(&Bs[sr][sk + 8]) = *reinterpret_cast<const uint4*>(pb + k0 + 8);
    __syncthreads();
    bf16x8 af[4], bfv[4];
#pragma unroll
    for (int m = 0; m < 4; m++)
      af[m] = as_bf(*reinterpret_cast<const us8v*>(&As[wr * 64 + m * 16 + c][g * 8]));
#pragma unroll
    for (int n = 0; n < 4; n++)
      bfv[n] = as_bf(*reinterpret_cast<const us8v*>(&Bs[wc * 64 + n * 16 + c][g * 8]));
#pragma unroll
    for (int m = 0; m < 4; m++)
#pragma unroll
      for (int n = 0; n < 4; n++) acc[m][n] = mfma16(af[m], bfv[n], acc[m][n]);
    __syncthreads();
  }
#pragma unroll
  for (int m = 0; m < 4; m++)
#pragma unroll
    for (int n = 0; n < 4; n++)
#pragma unroll
      for (int r = 0; r < 4; r++)
        C[(size_t)(m0 + wr * 64 + m * 16 + g * 4 + r) * N + n0 + wc * 64 + n * 16 + c] =
            acc[m][n][r];
}

// ---------------- Flash attention: swapped-QK^T 32x32 MFMA, register-pipelined ----------------
// Wave owns 32 q rows (q = lane&31). S-tile: lane holds S[kv=(r&3)+8*(r>>2)+4*hi][q=lane&31].
// K ping-pong prefetched one step ahead in regs; V issued at step start (hidden by QK^T+softmax).
__global__ __launch_bounds__(256, 2) void attn32_kernel(const unsigned short* __restrict__ Q,
                                                        const unsigned short* __restrict__ Kc,
                                                        const unsigned short* __restrict__ Vt,
                                                        unsigned short* __restrict__ O) {
  int t = threadIdx.x;
  int lane = t & 63, wid = t >> 6;
  int l31 = lane & 31, hi = lane >> 5;
  int qi = (int)gridDim.x - 1 - (int)blockIdx.x;  // heavy q-tiles dispatched first
  int bh = blockIdx.y;
  int b = bh >> 4, h = bh & 15, kvh = h >> 2;
  int qw = qi * 128 + wid * 32;

  const unsigned short* Qp = Q + ((size_t)(b * NH + h) * S_ + qw) * HD + (size_t)l31 * HD + hi * 8;
  const unsigned short* Kp = Kc + (size_t)(b * NKV + kvh) * S_ * HD + (size_t)l31 * HD + hi * 8;
  const unsigned short* Vp = Vt + (size_t)(b * NKV + kvh) * HD * S_ + (size_t)l31 * S_ + hi * 8;

  bf16x8 qf[8];
#pragma unroll
  for (int kk = 0; kk < 8; kk++)
    qf[kk] = as_bf(*reinterpret_cast<const us8v*>(Qp + kk * 16));

  f32x16 oacc[4] = {};
  float mrow = -1e30f, lsum = 0.0f;

  bf16x8 kA[8], kB[8];

  auto loadK = [&](bf16x8(&kf)[8], int kv) {
    const unsigned short* kp = Kp + (size_t)kv * HD;
#pragma unroll
    for (int kk = 0; kk < 8; kk++)
      kf[kk] = as_bf(*reinterpret_cast<const us8v*>(kp + kk * 16));
  };

  auto step = [&](bf16x8(&kf)[8], bf16x8(&kn)[8], int kv0) {
    // V loads for this tile issue first: latency hides under QK^T + softmax
    bf16x8 vf[8];
    const unsigned short* vp = Vp + kv0;
#pragma unroll
    for (int dt = 0; dt < 4; dt++) {
      vf[2 * dt] = as_bf(*reinterpret_cast<const us8v*>(vp + (size_t)dt * 32 * S_));
      vf[2 * dt + 1] = as_bf(*reinterpret_cast<const us8v*>(vp + (size_t)dt * 32 * S_ + 16));
    }
    // prefetch next K tile (consumed one full step later)
    if (kv0 + 32 <= qw) loadK(kn, kv0 + 32);

    // ---- QK^T: S[kv][q], A=K rows, B=Q cols ----
    f32x16 s = {};
    __builtin_amdgcn_s_setprio(1);
#pragma unroll
    for (int kk = 0; kk < 8; kk++) s = mfma32(kf[kk], qf[kk], s);
    __builtin_amdgcn_s_setprio(0);

    if (kv0 == qw) {  // diagonal block: causal mask
      int qg = qw + l31;
#pragma unroll
      for (int r = 0; r < 16; r++) {
        int kvg = kv0 + (r & 3) + 8 * (r >> 2) + 4 * hi;
        if (kvg > qg) s[r] = -1e30f;
      }
    }

    // ---- online softmax (lane-local row; partner = lane^32) ----
    float pm = fmaxf(s[0], s[1]);
#pragma unroll
    for (int r = 2; r < 16; r++) pm = fmaxf(pm, s[r]);
    pm = fmaxf(pm, __shfl_xor(pm, 32));

    bool nore = __all(pm <= mrow + 8.0f) != 0;  // defer-max (T13), wave-uniform
    float mn = nore ? mrow : fmaxf(mrow, pm);
    float part = 0.0f;
    uint32_t w[8];
#pragma unroll
    for (int j = 0; j < 8; j++) {
      float e0 = __expf(s[2 * j] - mn);
      float e1 = __expf(s[2 * j + 1] - mn);
      part += e0 + e1;
      w[j] = pk2(e0, e1);
    }
    part += __shfl_xor(part, 32);
    if (nore) {
      lsum += part;
    } else {
      float alpha = __expf(mrow - mn);
      lsum = lsum * alpha + part;
      mrow = mn;
#pragma unroll
      for (int dt = 0; dt < 4; dt++)
#pragma unroll
        for (int r = 0; r < 16; r++) oacc[dt][r] *= alpha;
    }

    // ---- P -> A-fragments (kv ascending) via lane^32 exchange ----
    uint32_t sw[8];
#pragma unroll
    for (int j = 0; j < 8; j++) sw[j] = __shfl_xor(w[j], 32);
    union { uint32_t u[4]; bf16x8 v; } pa0, pa1;
    if (hi == 0) {
      pa0.u[0] = w[0]; pa0.u[1] = w[1]; pa0.u[2] = sw[0]; pa0.u[3] = sw[1];
      pa1.u[0] = w[4]; pa1.u[1] = w[5]; pa1.u[2] = sw[4]; pa1.u[3] = sw[5];
    } else {
      pa0.u[0] = sw[2]; pa0.u[1] = sw[3]; pa0.u[2] = w[2]; pa0.u[3] = w[3];
      pa1.u[0] = sw[6]; pa1.u[1] = sw[7]; pa1.u[2] = w[6]; pa1.u[3] = w[7];
    }

    // ---- PV: O[q][d] += P * V ----
    __builtin_amdgcn_s_setprio(1);
#pragma unroll
    for (int dt = 0; dt < 4; dt++) {
      oacc[dt] = mfma32(pa0.v, vf[2 * dt], oacc[dt]);
      oacc[dt] = mfma32(pa1.v, vf[2 * dt + 1], oacc[dt]);
    }
    __builtin_amdgcn_s_setprio(0);
  };

  loadK(kA, 0);
  int kv0 = 0;
  while (true) {
    step(kA, kB, kv0);
    kv0 += 32;
    if (kv0 > qw) break;
    step(kB, kA, kv0);
    kv0 += 32;
    if (kv0 > qw) break;
  }

  // ---- epilogue: O[q=crow(r,hi)][d=dt*32+l31] ----
  float il = 1.0f / lsum;
  unsigned short* Op = O + ((size_t)b * S_ + qw) * D_ + h * HD;
#pragma unroll
  for (int r = 0; r < 16; r++) {
    int row = (r & 3) + 8 * (r >> 2) + 4 * hi;
    float sc = __shfl(il, row);
#pragma unroll
    for (int dt = 0; dt < 4; dt++)
      Op[(size_t)row * D_ + dt * 32 + l31] = f2b(oacc[dt][r] * sc);
  }
}

extern "C" void kernel_launch(void* const* d_in, const int* in_sizes, int n_in, void* d_out,
                              int out_size, void* d_ws, size_t ws_size, hipStream_t stream) {
  const float* x = (const float*)d_in[0];
  const float* w_qkv = (const float*)d_in[1];
  const float* w_o = (const float*)d_in[2];
  float* out = (float*)d_out;

  char* ws = (char*)d_ws;
  size_t off = 0;
  auto alloc = [&](size_t bytes) -> void* {
    void* p = ws + off;
    off += (bytes + 255) & ~(size_t)255;
    return p;
  };
  const size_t nx = (size_t)B_ * S_ * D_;
  const size_t nwqkv = (size_t)QKV_O * D_;
  const size_t nwo = (size_t)D_ * D_;
  unsigned short* xb = (unsigned short*)alloc(nx * 2);
  unsigned short* wqkvb = (unsigned short*)alloc(nwqkv * 2);
  unsigned short* wob = (unsigned short*)alloc(nwo * 2);
  float* qkv = (float*)alloc((size_t)B_ * S_ * QKV_O * 4);
  unsigned short* Qb = (unsigned short*)alloc((size_t)B_ * NH * S_ * HD * 2);
  unsigned short* Kb = (unsigned short*)alloc((size_t)B_ * NKV * S_ * HD * 2);
  unsigned short* Vtb = (unsigned short*)alloc((size_t)B_ * NKV * HD * S_ * 2);
  unsigned short* attnb = (unsigned short*)alloc((size_t)B_ * S_ * D_ * 2);
  float* cs = (float*)alloc((size_t)S_ * 64 * 4);
  float* sn = (float*)alloc((size_t)S_ * 64 * 4);

  f2b_kernel<<<dim3((nx / 4 + 255) / 256), 256, 0, stream>>>(x, xb, nx / 4);
  f2b_kernel<<<dim3((nwqkv / 4 + 255) / 256), 256, 0, stream>>>(w_qkv, wqkvb, nwqkv / 4);
  f2b_kernel<<<dim3((nwo / 4 + 255) / 256), 256, 0, stream>>>(w_o, wob, nwo / 4);
  rope_table_kernel<<<dim3((S_ * 64 + 255) / 256), 256, 0, stream>>>(cs, sn);

  gemm_bt_kernel<<<dim3(QKV_O / 128, (B_ * S_) / 128), 256, 0, stream>>>(xb, wqkvb, qkv,
                                                                         B_ * S_, QKV_O, D_);

  rope_qk_kernel<<<dim3((B_ * S_ * 20 * 64 + 255) / 256), 256, 0, stream>>>(qkv, cs, sn, Qb, Kb);
  vt_kernel<<<dim3(S_ / 32, HD / 32, B_ * NKV), 256, 0, stream>>>(qkv, Vtb);

  attn32_kernel<<<dim3(16, 32), 256, 0, stream>>>(Qb, Kb, Vtb, attnb);

  gemm_bt_kernel<<<dim3(D_ / 128, (B_ * S_) / 128), 256, 0, stream>>>(attnb, wob, out,
                                                                      B_ * S_, D_, D_);
}

// Round 4
// 271.341 us; speedup vs baseline: 1.9568x; 1.4820x over previous
//
#include <hip/hip_runtime.h>
#include <hip/hip_bf16.h>
#include <cstdint>
#include <cstddef>

typedef float f32x4 __attribute__((ext_vector_type(4)));
typedef float f32x16 __attribute__((ext_vector_type(16)));
typedef __bf16 bf16x8 __attribute__((ext_vector_type(8)));
typedef unsigned short us8v __attribute__((ext_vector_type(8)));
typedef unsigned short us4v __attribute__((ext_vector_type(4)));

constexpr int B_ = 2, S_ = 2048, D_ = 2048, NH = 16, NKV = 4, HD = 128;
constexpr int QKV_O = (NH + 2 * NKV) * HD;  // 3072

__device__ __forceinline__ unsigned short f2b(float f) {
  union { float f; uint32_t u; } v{f};
  uint32_t r = v.u + 0x7fffu + ((v.u >> 16) & 1u);  // RNE
  return (unsigned short)(r >> 16);
}

__device__ __forceinline__ uint32_t pk2(float a, float b) {
  union { __bf16 h[2]; uint32_t u; } v;
  v.h[0] = (__bf16)a; v.h[1] = (__bf16)b;
  return v.u;
}

__device__ __forceinline__ bf16x8 as_bf(us8v x) {
  union { us8v u; bf16x8 b; } v; v.u = x; return v.b;
}

__device__ __forceinline__ f32x4 mfma16(bf16x8 a, bf16x8 b, f32x4 c) {
  return __builtin_amdgcn_mfma_f32_16x16x32_bf16(a, b, c, 0, 0, 0);
}
__device__ __forceinline__ f32x16 mfma32(bf16x8 a, bf16x8 b, f32x16 c) {
  return __builtin_amdgcn_mfma_f32_32x32x16_bf16(a, b, c, 0, 0, 0);
}

// ---------------- f32 -> bf16 conversion (vectorized) ----------------
__global__ void f2b_kernel(const float* __restrict__ in, unsigned short* __restrict__ out, int n4) {
  int i = blockIdx.x * blockDim.x + threadIdx.x;
  if (i >= n4) return;
  float4 v = reinterpret_cast<const float4*>(in)[i];
  us4v o;
  o[0] = f2b(v.x); o[1] = f2b(v.y); o[2] = f2b(v.z); o[3] = f2b(v.w);
  reinterpret_cast<us4v*>(out)[i] = o;
}

// ---------------- RoPE cos/sin table: [S][64] ----------------
__global__ void rope_table_kernel(float* __restrict__ cs, float* __restrict__ sn) {
  int idx = blockIdx.x * blockDim.x + threadIdx.x;
  if (idx >= S_ * 64) return;
  int t = idx >> 6, i = idx & 63;
  float inv = __expf(-((float)(2 * i) / 128.0f) * 9.210340371976184f);
  float fr = (float)t * inv;
  cs[idx] = cosf(fr);
  sn[idx] = sinf(fr);
}

// ---------------- RoPE apply; Q -> [b,h,s,d] (pre-scaled), K -> K2 [bk][d/8][s][8] ----------------
__global__ void rope_qk_kernel(const float* __restrict__ qkv, const float* __restrict__ cs,
                               const float* __restrict__ sn, unsigned short* __restrict__ Q,
                               unsigned short* __restrict__ K2) {
  int idx = blockIdx.x * blockDim.x + threadIdx.x;
  if (idx >= B_ * S_ * 20 * 64) return;
  int pr = idx & 63;
  int tmp = idx >> 6;
  int hh = tmp % 20; tmp /= 20;
  int s = tmp % S_;
  int b = tmp / S_;
  int off = (hh < 16) ? hh * HD : NH * HD + (hh - 16) * HD;
  float2 v = *reinterpret_cast<const float2*>(qkv + (size_t)(b * S_ + s) * QKV_O + off + 2 * pr);
  float c0 = cs[s * 64 + pr], s0 = sn[s * 64 + pr];
  float mult = (hh < 16) ? 0.08838834764831845f : 1.0f;  // fold attn scale into Q
  float o0 = (v.x * c0 - v.y * s0) * mult;
  float o1 = (v.x * s0 + v.y * c0) * mult;
  unsigned int packed = (unsigned)f2b(o0) | ((unsigned)f2b(o1) << 16);
  if (hh < 16) {
    *reinterpret_cast<unsigned*>(Q + (((size_t)(b * NH + hh) * S_ + s) * HD + 2 * pr)) = packed;
  } else {
    int bk = b * NKV + (hh - 16);
    // element d = 2*pr: K2[((bk*16 + d/8)*S + s)*8 + d%8]
    size_t a = (((size_t)bk * 16 + (pr >> 2)) * S_ + s) * 8 + (pr & 3) * 2;
    *reinterpret_cast<unsigned*>(K2 + a) = packed;
  }
}

// ---------------- V pack: qkv f32 -> V2 bf16 [bk][s/8][d=128][8] ----------------
__global__ __launch_bounds__(128) void v8_kernel(const float* __restrict__ qkv,
                                                 unsigned short* __restrict__ V2) {
  int d = threadIdx.x;          // 0..127
  int g = blockIdx.x;           // s-group 0..255
  int bk = blockIdx.y;          // b*4+kvh
  const float* src = qkv + (size_t)((bk >> 2) * S_ + g * 8) * QKV_O + (NH + NKV) * HD +
                     (bk & 3) * HD + d;
  us8v o;
#pragma unroll
  for (int j = 0; j < 8; j++) o[j] = f2b(src[(size_t)j * QKV_O]);
  *reinterpret_cast<us8v*>(V2 + (((size_t)bk * 256 + g) * 128 + d) * 8) = o;
}

// ---------------- bf16 GEMM: C[M,N] = A[M,K] * B[N,K]^T (f32 out) ----------------
__global__ __launch_bounds__(256) void gemm_bt_kernel(const unsigned short* __restrict__ A,
                                                      const unsigned short* __restrict__ Bm,
                                                      float* __restrict__ C, int M, int N, int K) {
  __shared__ unsigned short As[128][40];
  __shared__ unsigned short Bs[128][40];
  int t = threadIdx.x;
  int lane = t & 63, wid = t >> 6;
  int wr = wid >> 1, wc = wid & 1;  // 2x2 wave grid, each wave 64x64
  int g = lane >> 4, c = lane & 15;
  int m0 = blockIdx.y * 128, n0 = blockIdx.x * 128;
  int sr = t >> 1, sk = (t & 1) * 16;
  const unsigned short* pa = A + (size_t)(m0 + sr) * K + sk;
  const unsigned short* pb = Bm + (size_t)(n0 + sr) * K + sk;
  f32x4 acc[4][4] = {};
  for (int k0 = 0; k0 < K; k0 += 32) {
    *reinterpret_cast<uint4*>(&As[sr][sk]) = *reinterpret_cast<const uint4*>(pa + k0);
    *reinterpret_cast<uint4*>(&As[sr][sk + 8]) = *reinterpret_cast<const uint4*>(pa + k0 + 8);
    *reinterpret_cast<uint4*>(&Bs[sr][sk]) = *reinterpret_cast<const uint4*>(pb + k0);
    *reinterpret_cast<uint4*>(&Bs[sr][sk + 8]) = *reinterpret_cast<const uint4*>(pb + k0 + 8);
    __syncthreads();
    bf16x8 af[4], bfv[4];
#pragma unroll
    for (int m = 0; m < 4; m++)
      af[m] = as_bf(*reinterpret_cast<const us8v*>(&As[wr * 64 + m * 16 + c][g * 8]));
#pragma unroll
    for (int n = 0; n < 4; n++)
      bfv[n] = as_bf(*reinterpret_cast<const us8v*>(&Bs[wc * 64 + n * 16 + c][g * 8]));
#pragma unroll
    for (int m = 0; m < 4; m++)
#pragma unroll
      for (int n = 0; n < 4; n++) acc[m][n] = mfma16(af[m], bfv[n], acc[m][n]);
    __syncthreads();
  }
#pragma unroll
  for (int m = 0; m < 4; m++)
#pragma unroll
    for (int n = 0; n < 4; n++)
#pragma unroll
      for (int r = 0; r < 4; r++)
        C[(size_t)(m0 + wr * 64 + m * 16 + g * 4 + r) * N + n0 + wc * 64 + n * 16 + c] =
            acc[m][n][r];
}

// ---------------- Flash attention: swapped-QK^T 32x32 MFMA, coalesced K2/V2 ----------------
// Wave owns 32 q rows (q = lane&31). S-tile: lane holds S[kv=(r&3)+8*(r>>2)+4*hi][q=lane&31].
// K2 [bk][d/8][s][8]: A-frag load = 512B contiguous. V2 [bk][s/8][d][8]: B-frag = 512B contiguous.
__global__ __launch_bounds__(256, 2) void attn32_kernel(const unsigned short* __restrict__ Q,
                                                        const unsigned short* __restrict__ K2,
                                                        const unsigned short* __restrict__ V2,
                                                        unsigned short* __restrict__ O) {
  int t = threadIdx.x;
  int lane = t & 63, wid = t >> 6;
  int l31 = lane & 31, hi = lane >> 5;
  int qi = (int)gridDim.x - 1 - (int)blockIdx.x;
  int bh = blockIdx.y;
  int b = bh >> 4, h = bh & 15, kvh = h >> 2;
  int bk = b * NKV + kvh;
  int qw = qi * 128 + wid * 32;

  const unsigned short* Qp = Q + ((size_t)(b * NH + h) * S_ + qw) * HD + (size_t)l31 * HD + hi * 8;
  // K2 base: element offset ((bk*16 + kk*2 + hi)*S + kv + l31)*8
  const unsigned short* Kp = K2 + (((size_t)bk * 16 + hi) * S_ + l31) * 8;
  // V2 base: element offset ((bk*256 + kv0/8 + half*2 + hi)*128 + dt*32 + l31)*8
  const unsigned short* Vp = V2 + (((size_t)bk * 256 + hi) * 128 + l31) * 8;

  bf16x8 qf[8];
#pragma unroll
  for (int kk = 0; kk < 8; kk++)
    qf[kk] = as_bf(*reinterpret_cast<const us8v*>(Qp + kk * 16));

  f32x16 oacc[4] = {};
  float mrow = -1e30f, lsum = 0.0f;

  bf16x8 kA[8], kB[8];

  auto loadK = [&](bf16x8(&kf)[8], int kv) {
    const unsigned short* kp = Kp + (size_t)kv * 8;
#pragma unroll
    for (int kk = 0; kk < 8; kk++)
      kf[kk] = as_bf(*reinterpret_cast<const us8v*>(kp + (size_t)kk * 2 * S_ * 8));
  };

  auto step = [&](bf16x8(&kf)[8], bf16x8(&kn)[8], int kv0) {
    // V loads for this tile issue first: latency hides under QK^T + softmax
    bf16x8 vf[8];
    const unsigned short* vp = Vp + (size_t)kv0 * 128;  // (kv0/8)*128*8 elems
#pragma unroll
    for (int dt = 0; dt < 4; dt++) {
      vf[2 * dt] = as_bf(*reinterpret_cast<const us8v*>(vp + dt * 256));
      vf[2 * dt + 1] = as_bf(*reinterpret_cast<const us8v*>(vp + 2048 + dt * 256));
    }
    // prefetch next K tile (consumed one full step later)
    if (kv0 + 32 <= qw) loadK(kn, kv0 + 32);

    // ---- QK^T: S[kv][q], two independent MFMA chains ----
    f32x16 sa = {}, sb = {};
    __builtin_amdgcn_s_setprio(1);
#pragma unroll
    for (int kk = 0; kk < 4; kk++) {
      sa = mfma32(kf[2 * kk], qf[2 * kk], sa);
      sb = mfma32(kf[2 * kk + 1], qf[2 * kk + 1], sb);
    }
    __builtin_amdgcn_s_setprio(0);
    f32x16 s = sa + sb;

    if (kv0 == qw) {  // diagonal block: causal mask
      int qg = qw + l31;
#pragma unroll
      for (int r = 0; r < 16; r++) {
        int kvg = kv0 + (r & 3) + 8 * (r >> 2) + 4 * hi;
        if (kvg > qg) s[r] = -1e30f;
      }
    }

    // ---- online softmax (lane-local row; partner = lane^32) ----
    float pm = fmaxf(s[0], s[1]);
#pragma unroll
    for (int r = 2; r < 16; r++) pm = fmaxf(pm, s[r]);
    pm = fmaxf(pm, __shfl_xor(pm, 32));

    bool nore = __all(pm <= mrow + 8.0f) != 0;  // defer-max (T13), wave-uniform
    float mn = nore ? mrow : fmaxf(mrow, pm);
    float part = 0.0f;
    uint32_t w[8];
#pragma unroll
    for (int j = 0; j < 8; j++) {
      float e0 = __expf(s[2 * j] - mn);
      float e1 = __expf(s[2 * j + 1] - mn);
      part += e0 + e1;
      w[j] = pk2(e0, e1);
    }
    part += __shfl_xor(part, 32);
    if (nore) {
      lsum += part;
    } else {
      float alpha = __expf(mrow - mn);
      lsum = lsum * alpha + part;
      mrow = mn;
#pragma unroll
      for (int dt = 0; dt < 4; dt++)
#pragma unroll
        for (int r = 0; r < 16; r++) oacc[dt][r] *= alpha;
    }

    // ---- P -> A-fragments (kv ascending) via lane^32 exchange ----
    uint32_t sw[8];
#pragma unroll
    for (int j = 0; j < 8; j++) sw[j] = __shfl_xor(w[j], 32);
    union { uint32_t u[4]; bf16x8 v; } pa0, pa1;
    if (hi == 0) {
      pa0.u[0] = w[0]; pa0.u[1] = w[1]; pa0.u[2] = sw[0]; pa0.u[3] = sw[1];
      pa1.u[0] = w[4]; pa1.u[1] = w[5]; pa1.u[2] = sw[4]; pa1.u[3] = sw[5];
    } else {
      pa0.u[0] = sw[2]; pa0.u[1] = sw[3]; pa0.u[2] = w[2]; pa0.u[3] = w[3];
      pa1.u[0] = sw[6]; pa1.u[1] = sw[7]; pa1.u[2] = w[6]; pa1.u[3] = w[7];
    }

    // ---- PV: O[q][d] += P * V ----
    __builtin_amdgcn_s_setprio(1);
#pragma unroll
    for (int dt = 0; dt < 4; dt++) {
      oacc[dt] = mfma32(pa0.v, vf[2 * dt], oacc[dt]);
      oacc[dt] = mfma32(pa1.v, vf[2 * dt + 1], oacc[dt]);
    }
    __builtin_amdgcn_s_setprio(0);
  };

  loadK(kA, 0);
  int kv0 = 0;
  while (true) {
    step(kA, kB, kv0);
    kv0 += 32;
    if (kv0 > qw) break;
    step(kB, kA, kv0);
    kv0 += 32;
    if (kv0 > qw) break;
  }

  // ---- epilogue: O[q=crow(r,hi)][d=dt*32+l31] ----
  float il = 1.0f / lsum;
  unsigned short* Op = O + ((size_t)b * S_ + qw) * D_ + h * HD;
#pragma unroll
  for (int r = 0; r < 16; r++) {
    int row = (r & 3) + 8 * (r >> 2) + 4 * hi;
    float sc = __shfl(il, row);
#pragma unroll
    for (int dt = 0; dt < 4; dt++)
      Op[(size_t)row * D_ + dt * 32 + l31] = f2b(oacc[dt][r] * sc);
  }
}

extern "C" void kernel_launch(void* const* d_in, const int* in_sizes, int n_in, void* d_out,
                              int out_size, void* d_ws, size_t ws_size, hipStream_t stream) {
  const float* x = (const float*)d_in[0];
  const float* w_qkv = (const float*)d_in[1];
  const float* w_o = (const float*)d_in[2];
  float* out = (float*)d_out;

  char* ws = (char*)d_ws;
  size_t off = 0;
  auto alloc = [&](size_t bytes) -> void* {
    void* p = ws + off;
    off += (bytes + 255) & ~(size_t)255;
    return p;
  };
  const size_t nx = (size_t)B_ * S_ * D_;
  const size_t nwqkv = (size_t)QKV_O * D_;
  const size_t nwo = (size_t)D_ * D_;
  unsigned short* xb = (unsigned short*)alloc(nx * 2);
  unsigned short* wqkvb = (unsigned short*)alloc(nwqkv * 2);
  unsigned short* wob = (unsigned short*)alloc(nwo * 2);
  float* qkv = (float*)alloc((size_t)B_ * S_ * QKV_O * 4);
  unsigned short* Qb = (unsigned short*)alloc((size_t)B_ * NH * S_ * HD * 2);
  unsigned short* K2b = (unsigned short*)alloc((size_t)B_ * NKV * S_ * HD * 2);
  unsigned short* V2b = (unsigned short*)alloc((size_t)B_ * NKV * HD * S_ * 2);
  unsigned short* attnb = (unsigned short*)alloc((size_t)B_ * S_ * D_ * 2);
  float* cs = (float*)alloc((size_t)S_ * 64 * 4);
  float* sn = (float*)alloc((size_t)S_ * 64 * 4);

  f2b_kernel<<<dim3((nx / 4 + 255) / 256), 256, 0, stream>>>(x, xb, nx / 4);
  f2b_kernel<<<dim3((nwqkv / 4 + 255) / 256), 256, 0, stream>>>(w_qkv, wqkvb, nwqkv / 4);
  f2b_kernel<<<dim3((nwo / 4 + 255) / 256), 256, 0, stream>>>(w_o, wob, nwo / 4);
  rope_table_kernel<<<dim3((S_ * 64 + 255) / 256), 256, 0, stream>>>(cs, sn);

  gemm_bt_kernel<<<dim3(QKV_O / 128, (B_ * S_) / 128), 256, 0, stream>>>(xb, wqkvb, qkv,
                                                                         B_ * S_, QKV_O, D_);

  rope_qk_kernel<<<dim3((B_ * S_ * 20 * 64 + 255) / 256), 256, 0, stream>>>(qkv, cs, sn, Qb, K2b);
  v8_kernel<<<dim3(S_ / 8, B_ * NKV), 128, 0, stream>>>(qkv, V2b);

  attn32_kernel<<<dim3(16, 32), 256, 0, stream>>>(Qb, K2b, V2b, attnb);

  gemm_bt_kernel<<<dim3(D_ / 128, (B_ * S_) / 128), 256, 0, stream>>>(attnb, wob, out,
                                                                      B_ * S_, D_, D_);
}

// Round 5
// 257.933 us; speedup vs baseline: 2.0585x; 1.0520x over previous
//
#include <hip/hip_runtime.h>
#include <hip/hip_bf16.h>
#include <cstdint>
#include <cstddef>

typedef float f32x4 __attribute__((ext_vector_type(4)));
typedef float f32x16 __attribute__((ext_vector_type(16)));
typedef __bf16 bf16x8 __attribute__((ext_vector_type(8)));
typedef unsigned short us8v __attribute__((ext_vector_type(8)));
typedef unsigned short us4v __attribute__((ext_vector_type(4)));

constexpr int B_ = 2, S_ = 2048, D_ = 2048, NH = 16, NKV = 4, HD = 128;
constexpr int QKV_O = (NH + 2 * NKV) * HD;  // 3072

__device__ __forceinline__ unsigned short f2b(float f) {
  union { float f; uint32_t u; } v{f};
  uint32_t r = v.u + 0x7fffu + ((v.u >> 16) & 1u);  // RNE
  return (unsigned short)(r >> 16);
}

__device__ __forceinline__ uint32_t pk2(float a, float b) {
  union { __bf16 h[2]; uint32_t u; } v;
  v.h[0] = (__bf16)a; v.h[1] = (__bf16)b;
  return v.u;
}

__device__ __forceinline__ bf16x8 as_bf(us8v x) {
  union { us8v u; bf16x8 b; } v; v.u = x; return v.b;
}

__device__ __forceinline__ f32x4 mfma16(bf16x8 a, bf16x8 b, f32x4 c) {
  return __builtin_amdgcn_mfma_f32_16x16x32_bf16(a, b, c, 0, 0, 0);
}
__device__ __forceinline__ f32x16 mfma32(bf16x8 a, bf16x8 b, f32x16 c) {
  return __builtin_amdgcn_mfma_f32_32x32x16_bf16(a, b, c, 0, 0, 0);
}

// async global->LDS, 16B per lane; LDS dest = wave-uniform base + lane*16
__device__ __forceinline__ void gload_lds16(const unsigned short* g, unsigned short* l) {
  __builtin_amdgcn_global_load_lds(
      (const __attribute__((address_space(1))) unsigned int*)(uintptr_t)g,
      (__attribute__((address_space(3))) unsigned int*)(uintptr_t)l, 16, 0, 0);
}

// ---------------- f32 -> bf16 conversion (vectorized) ----------------
__global__ void f2b_kernel(const float* __restrict__ in, unsigned short* __restrict__ out, int n4) {
  int i = blockIdx.x * blockDim.x + threadIdx.x;
  if (i >= n4) return;
  float4 v = reinterpret_cast<const float4*>(in)[i];
  us4v o;
  o[0] = f2b(v.x); o[1] = f2b(v.y); o[2] = f2b(v.z); o[3] = f2b(v.w);
  reinterpret_cast<us4v*>(out)[i] = o;
}

// ---------------- RoPE cos/sin table: [S][64] ----------------
__global__ void rope_table_kernel(float* __restrict__ cs, float* __restrict__ sn) {
  int idx = blockIdx.x * blockDim.x + threadIdx.x;
  if (idx >= S_ * 64) return;
  int t = idx >> 6, i = idx & 63;
  float inv = __expf(-((float)(2 * i) / 128.0f) * 9.210340371976184f);
  float fr = (float)t * inv;
  cs[idx] = cosf(fr);
  sn[idx] = sinf(fr);
}

// ---------------- RoPE apply; Q -> [b,h,s,d] (pre-scaled), K -> K2 [bk][d/8][s][8] ----------------
__global__ void rope_qk_kernel(const float* __restrict__ qkv, const float* __restrict__ cs,
                               const float* __restrict__ sn, unsigned short* __restrict__ Q,
                               unsigned short* __restrict__ K2) {
  int idx = blockIdx.x * blockDim.x + threadIdx.x;
  if (idx >= B_ * S_ * 20 * 64) return;
  int pr = idx & 63;
  int tmp = idx >> 6;
  int hh = tmp % 20; tmp /= 20;
  int s = tmp % S_;
  int b = tmp / S_;
  int off = (hh < 16) ? hh * HD : NH * HD + (hh - 16) * HD;
  float2 v = *reinterpret_cast<const float2*>(qkv + (size_t)(b * S_ + s) * QKV_O + off + 2 * pr);
  float c0 = cs[s * 64 + pr], s0 = sn[s * 64 + pr];
  float mult = (hh < 16) ? 0.08838834764831845f : 1.0f;  // fold attn scale into Q
  float o0 = (v.x * c0 - v.y * s0) * mult;
  float o1 = (v.x * s0 + v.y * c0) * mult;
  unsigned int packed = (unsigned)f2b(o0) | ((unsigned)f2b(o1) << 16);
  if (hh < 16) {
    *reinterpret_cast<unsigned*>(Q + (((size_t)(b * NH + hh) * S_ + s) * HD + 2 * pr)) = packed;
  } else {
    int bk = b * NKV + (hh - 16);
    size_t a = (((size_t)bk * 16 + (pr >> 2)) * S_ + s) * 8 + (pr & 3) * 2;
    *reinterpret_cast<unsigned*>(K2 + a) = packed;
  }
}

// ---------------- V pack: qkv f32 -> V2 bf16 [bk][s/8][d=128][8] ----------------
__global__ __launch_bounds__(128) void v8_kernel(const float* __restrict__ qkv,
                                                 unsigned short* __restrict__ V2) {
  int d = threadIdx.x;          // 0..127
  int g = blockIdx.x;           // s-group 0..255
  int bk = blockIdx.y;          // b*4+kvh
  const float* src = qkv + (size_t)((bk >> 2) * S_ + g * 8) * QKV_O + (NH + NKV) * HD +
                     (bk & 3) * HD + d;
  us8v o;
#pragma unroll
  for (int j = 0; j < 8; j++) o[j] = f2b(src[(size_t)j * QKV_O]);
  *reinterpret_cast<us8v*>(V2 + (((size_t)bk * 256 + g) * 128 + d) * 8) = o;
}

// ---------------- bf16 GEMM (m97 structure): C[M,N] = A[M,K] * B[N,K]^T ----------------
// Linear LDS [128][32], staged via global_load_lds dwordx4 (4 per wave per K-step).
__global__ __launch_bounds__(256) void gemm_bt_kernel(const unsigned short* __restrict__ A,
                                                      const unsigned short* __restrict__ Bm,
                                                      float* __restrict__ C, int M, int N, int K) {
  __shared__ unsigned short As[128 * 32];
  __shared__ unsigned short Bs[128 * 32];
  int t = threadIdx.x;
  int lane = t & 63, wid = t >> 6;
  int wr = wid >> 1, wc = wid & 1;  // 2x2 wave grid, each wave 64x64
  int g = lane >> 4, c = lane & 15;
  int m0 = blockIdx.y * 128, n0 = blockIdx.x * 128;

  // staging: wave wid covers rows wid*32 .. wid*32+31 (two 16-row groups)
  int r0 = wid * 32 + (lane >> 2);
  int cc = (lane & 3) * 8;
  const unsigned short* pa = A + (size_t)(m0 + r0) * K + cc;
  const unsigned short* pb = Bm + (size_t)(n0 + r0) * K + cc;
  unsigned short* lA = As + wid * 1024;  // wave-uniform base; +512 elems for 2nd group
  unsigned short* lB = Bs + wid * 1024;

  f32x4 acc[4][4] = {};
  for (int k0 = 0; k0 < K; k0 += 32) {
    gload_lds16(pa + k0, lA);
    gload_lds16(pa + (size_t)16 * K + k0, lA + 512);
    gload_lds16(pb + k0, lB);
    gload_lds16(pb + (size_t)16 * K + k0, lB + 512);
    __syncthreads();
    bf16x8 af[4], bfv[4];
#pragma unroll
    for (int m = 0; m < 4; m++)
      af[m] = as_bf(*reinterpret_cast<const us8v*>(&As[(wr * 64 + m * 16 + c) * 32 + g * 8]));
#pragma unroll
    for (int n = 0; n < 4; n++)
      bfv[n] = as_bf(*reinterpret_cast<const us8v*>(&Bs[(wc * 64 + n * 16 + c) * 32 + g * 8]));
#pragma unroll
    for (int m = 0; m < 4; m++)
#pragma unroll
      for (int n = 0; n < 4; n++) acc[m][n] = mfma16(af[m], bfv[n], acc[m][n]);
    __syncthreads();
  }
#pragma unroll
  for (int m = 0; m < 4; m++)
#pragma unroll
    for (int n = 0; n < 4; n++)
#pragma unroll
      for (int r = 0; r < 4; r++)
        C[(size_t)(m0 + wr * 64 + m * 16 + g * 4 + r) * N + n0 + wc * 64 + n * 16 + c] =
            acc[m][n][r];
}

// ---------------- Flash attention: swapped-QK^T 32x32 MFMA, coalesced K2/V2 ----------------
__global__ __launch_bounds__(256, 2) void attn32_kernel(const unsigned short* __restrict__ Q,
                                                        const unsigned short* __restrict__ K2,
                                                        const unsigned short* __restrict__ V2,
                                                        unsigned short* __restrict__ O) {
  int t = threadIdx.x;
  int lane = t & 63, wid = t >> 6;
  int l31 = lane & 31, hi = lane >> 5;
  int qi = (int)gridDim.x - 1 - (int)blockIdx.x;
  int bh = blockIdx.y;
  int b = bh >> 4, h = bh & 15, kvh = h >> 2;
  int bk = b * NKV + kvh;
  int qw = qi * 128 + wid * 32;

  const unsigned short* Qp = Q + ((size_t)(b * NH + h) * S_ + qw) * HD + (size_t)l31 * HD + hi * 8;
  const unsigned short* Kp = K2 + (((size_t)bk * 16 + hi) * S_ + l31) * 8;
  const unsigned short* Vp = V2 + (((size_t)bk * 256 + hi) * 128 + l31) * 8;

  bf16x8 qf[8];
#pragma unroll
  for (int kk = 0; kk < 8; kk++)
    qf[kk] = as_bf(*reinterpret_cast<const us8v*>(Qp + kk * 16));

  f32x16 oacc[4] = {};
  float mrow = -1e30f, lsum = 0.0f;

  bf16x8 kA[8], kB[8];

  auto loadK = [&](bf16x8(&kf)[8], int kv) {
    const unsigned short* kp = Kp + (size_t)kv * 8;
#pragma unroll
    for (int kk = 0; kk < 8; kk++)
      kf[kk] = as_bf(*reinterpret_cast<const us8v*>(kp + (size_t)kk * 2 * S_ * 8));
  };

  auto step = [&](bf16x8(&kf)[8], bf16x8(&kn)[8], int kv0) {
    bf16x8 vf[8];
    const unsigned short* vp = Vp + (size_t)kv0 * 128;
#pragma unroll
    for (int dt = 0; dt < 4; dt++) {
      vf[2 * dt] = as_bf(*reinterpret_cast<const us8v*>(vp + dt * 256));
      vf[2 * dt + 1] = as_bf(*reinterpret_cast<const us8v*>(vp + 2048 + dt * 256));
    }
    if (kv0 + 32 <= qw) loadK(kn, kv0 + 32);

    f32x16 sa = {}, sb = {};
    __builtin_amdgcn_s_setprio(1);
#pragma unroll
    for (int kk = 0; kk < 4; kk++) {
      sa = mfma32(kf[2 * kk], qf[2 * kk], sa);
      sb = mfma32(kf[2 * kk + 1], qf[2 * kk + 1], sb);
    }
    __builtin_amdgcn_s_setprio(0);
    f32x16 s = sa + sb;

    if (kv0 == qw) {
      int qg = qw + l31;
#pragma unroll
      for (int r = 0; r < 16; r++) {
        int kvg = kv0 + (r & 3) + 8 * (r >> 2) + 4 * hi;
        if (kvg > qg) s[r] = -1e30f;
      }
    }

    float pm = fmaxf(s[0], s[1]);
#pragma unroll
    for (int r = 2; r < 16; r++) pm = fmaxf(pm, s[r]);
    pm = fmaxf(pm, __shfl_xor(pm, 32));

    bool nore = __all(pm <= mrow + 8.0f) != 0;
    float mn = nore ? mrow : fmaxf(mrow, pm);
    float part = 0.0f;
    uint32_t w[8];
#pragma unroll
    for (int j = 0; j < 8; j++) {
      float e0 = __expf(s[2 * j] - mn);
      float e1 = __expf(s[2 * j + 1] - mn);
      part += e0 + e1;
      w[j] = pk2(e0, e1);
    }
    part += __shfl_xor(part, 32);
    if (nore) {
      lsum += part;
    } else {
      float alpha = __expf(mrow - mn);
      lsum = lsum * alpha + part;
      mrow = mn;
#pragma unroll
      for (int dt = 0; dt < 4; dt++)
#pragma unroll
        for (int r = 0; r < 16; r++) oacc[dt][r] *= alpha;
    }

    uint32_t sw[8];
#pragma unroll
    for (int j = 0; j < 8; j++) sw[j] = __shfl_xor(w[j], 32);
    union { uint32_t u[4]; bf16x8 v; } pa0, pa1;
    if (hi == 0) {
      pa0.u[0] = w[0]; pa0.u[1] = w[1]; pa0.u[2] = sw[0]; pa0.u[3] = sw[1];
      pa1.u[0] = w[4]; pa1.u[1] = w[5]; pa1.u[2] = sw[4]; pa1.u[3] = sw[5];
    } else {
      pa0.u[0] = sw[2]; pa0.u[1] = sw[3]; pa0.u[2] = w[2]; pa0.u[3] = w[3];
      pa1.u[0] = sw[6]; pa1.u[1] = sw[7]; pa1.u[2] = w[6]; pa1.u[3] = w[7];
    }

    __builtin_amdgcn_s_setprio(1);
#pragma unroll
    for (int dt = 0; dt < 4; dt++) {
      oacc[dt] = mfma32(pa0.v, vf[2 * dt], oacc[dt]);
      oacc[dt] = mfma32(pa1.v, vf[2 * dt + 1], oacc[dt]);
    }
    __builtin_amdgcn_s_setprio(0);
  };

  loadK(kA, 0);
  int kv0 = 0;
  while (true) {
    step(kA, kB, kv0);
    kv0 += 32;
    if (kv0 > qw) break;
    step(kB, kA, kv0);
    kv0 += 32;
    if (kv0 > qw) break;
  }

  float il = 1.0f / lsum;
  unsigned short* Op = O + ((size_t)b * S_ + qw) * D_ + h * HD;
#pragma unroll
  for (int r = 0; r < 16; r++) {
    int row = (r & 3) + 8 * (r >> 2) + 4 * hi;
    float sc = __shfl(il, row);
#pragma unroll
    for (int dt = 0; dt < 4; dt++)
      Op[(size_t)row * D_ + dt * 32 + l31] = f2b(oacc[dt][r] * sc);
  }
}

extern "C" void kernel_launch(void* const* d_in, const int* in_sizes, int n_in, void* d_out,
                              int out_size, void* d_ws, size_t ws_size, hipStream_t stream) {
  const float* x = (const float*)d_in[0];
  const float* w_qkv = (const float*)d_in[1];
  const float* w_o = (const float*)d_in[2];
  float* out = (float*)d_out;

  char* ws = (char*)d_ws;
  size_t off = 0;
  auto alloc = [&](size_t bytes) -> void* {
    void* p = ws + off;
    off += (bytes + 255) & ~(size_t)255;
    return p;
  };
  const size_t nx = (size_t)B_ * S_ * D_;
  const size_t nwqkv = (size_t)QKV_O * D_;
  const size_t nwo = (size_t)D_ * D_;
  unsigned short* xb = (unsigned short*)alloc(nx * 2);
  unsigned short* wqkvb = (unsigned short*)alloc(nwqkv * 2);
  unsigned short* wob = (unsigned short*)alloc(nwo * 2);
  float* qkv = (float*)alloc((size_t)B_ * S_ * QKV_O * 4);
  unsigned short* Qb = (unsigned short*)alloc((size_t)B_ * NH * S_ * HD * 2);
  unsigned short* K2b = (unsigned short*)alloc((size_t)B_ * NKV * S_ * HD * 2);
  unsigned short* V2b = (unsigned short*)alloc((size_t)B_ * NKV * HD * S_ * 2);
  unsigned short* attnb = (unsigned short*)alloc((size_t)B_ * S_ * D_ * 2);
  float* cs = (float*)alloc((size_t)S_ * 64 * 4);
  float* sn = (float*)alloc((size_t)S_ * 64 * 4);

  f2b_kernel<<<dim3((nx / 4 + 255) / 256), 256, 0, stream>>>(x, xb, nx / 4);
  f2b_kernel<<<dim3((nwqkv / 4 + 255) / 256), 256, 0, stream>>>(w_qkv, wqkvb, nwqkv / 4);
  f2b_kernel<<<dim3((nwo / 4 + 255) / 256), 256, 0, stream>>>(w_o, wob, nwo / 4);
  rope_table_kernel<<<dim3((S_ * 64 + 255) / 256), 256, 0, stream>>>(cs, sn);

  gemm_bt_kernel<<<dim3(QKV_O / 128, (B_ * S_) / 128), 256, 0, stream>>>(xb, wqkvb, qkv,
                                                                         B_ * S_, QKV_O, D_);

  rope_qk_kernel<<<dim3((B_ * S_ * 20 * 64 + 255) / 256), 256, 0, stream>>>(qkv, cs, sn, Qb, K2b);
  v8_kernel<<<dim3(S_ / 8, B_ * NKV), 128, 0, stream>>>(qkv, V2b);

  attn32_kernel<<<dim3(16, 32), 256, 0, stream>>>(Qb, K2b, V2b, attnb);

  gemm_bt_kernel<<<dim3(D_ / 128, (B_ * S_) / 128), 256, 0, stream>>>(attnb, wob, out,
                                                                      B_ * S_, D_, D_);
}